// Round 1
// baseline (1678.547 us; speedup 1.0000x reference)
//
#include <hip/hip_runtime.h>
#include <cstdint>

#define NN 50000
#define NE 640000

// ---------------- degree / dinv ----------------

__global__ void deg_kernel(const int* __restrict__ dst, float* __restrict__ deg) {
    int i = blockIdx.x * 256 + threadIdx.x;
    if (i < NE) unsafeAtomicAdd(&deg[dst[i]], 1.0f);
}

__global__ void dinv_kernel(float* __restrict__ deg) {
    int i = blockIdx.x * 256 + threadIdx.x;
    if (i < NN) deg[i] = rsqrtf(deg[i] + 1.0f);   // +1 for self-loop; in-place -> dinv
}

// ---------------- fp32 GEMM, K=128 fixed, 64x64 tile ----------------
// C[M x N] = A[M x 128] * B[128 x N]

__global__ __launch_bounds__(256) void gemm_k128(const float* __restrict__ A,
                                                 const float* __restrict__ B,
                                                 float* __restrict__ C,
                                                 int M, int N) {
    __shared__ float As[64][132];                 // padded: rows 4*132=528 apart -> 2-bank alias (free)
    __shared__ __align__(16) float Bs[128][64];
    const int t  = threadIdx.x;
    const int m0 = blockIdx.x * 64;
    const int n0 = blockIdx.y * 64;

    // load A tile (64 rows x 128 cols), coalesced float4
#pragma unroll
    for (int i = 0; i < 8; ++i) {
        int idx = i * 256 + t;
        int r = idx >> 5, c4 = idx & 31;
        int gm = m0 + r;
        float4 v = make_float4(0.f, 0.f, 0.f, 0.f);
        if (gm < M) v = *reinterpret_cast<const float4*>(&A[gm * 128 + c4 * 4]);
        As[r][c4 * 4 + 0] = v.x;
        As[r][c4 * 4 + 1] = v.y;
        As[r][c4 * 4 + 2] = v.z;
        As[r][c4 * 4 + 3] = v.w;
    }
    // load B tile (128 rows x 64 cols of the n0 panel), zero-fill past N
#pragma unroll
    for (int i = 0; i < 8; ++i) {
        int idx = i * 256 + t;
        int k = idx >> 4, c4 = idx & 15;
        int gn = n0 + c4 * 4;
        float4 v;
        v.x = (gn + 0 < N) ? B[k * N + gn + 0] : 0.f;
        v.y = (gn + 1 < N) ? B[k * N + gn + 1] : 0.f;
        v.z = (gn + 2 < N) ? B[k * N + gn + 2] : 0.f;
        v.w = (gn + 3 < N) ? B[k * N + gn + 3] : 0.f;
        *reinterpret_cast<float4*>(&Bs[k][c4 * 4]) = v;
    }
    __syncthreads();

    const int tx = t & 15, ty = t >> 4;
    float acc[4][4] = {};
#pragma unroll 8
    for (int k = 0; k < 128; ++k) {
        float a0 = As[ty * 4 + 0][k];
        float a1 = As[ty * 4 + 1][k];
        float a2 = As[ty * 4 + 2][k];
        float a3 = As[ty * 4 + 3][k];
        float4 b = *reinterpret_cast<const float4*>(&Bs[k][tx * 4]);
        acc[0][0] += a0 * b.x; acc[0][1] += a0 * b.y; acc[0][2] += a0 * b.z; acc[0][3] += a0 * b.w;
        acc[1][0] += a1 * b.x; acc[1][1] += a1 * b.y; acc[1][2] += a1 * b.z; acc[1][3] += a1 * b.w;
        acc[2][0] += a2 * b.x; acc[2][1] += a2 * b.y; acc[2][2] += a2 * b.z; acc[2][3] += a2 * b.w;
        acc[3][0] += a3 * b.x; acc[3][1] += a3 * b.y; acc[3][2] += a3 * b.z; acc[3][3] += a3 * b.w;
    }

#pragma unroll
    for (int i = 0; i < 4; ++i) {
        int gm = m0 + ty * 4 + i;
        if (gm >= M) continue;
        int gn = n0 + tx * 4;
        if (gn + 3 < N) {
            *reinterpret_cast<float4*>(&C[gm * N + gn]) =
                make_float4(acc[i][0], acc[i][1], acc[i][2], acc[i][3]);
        } else {
#pragma unroll
            for (int j = 0; j < 4; ++j)
                if (gn + j < N) C[gm * N + gn + j] = acc[i][j];
        }
    }
}

// ---------------- edge scatter (128 ch): one float4 per thread ----------------

__global__ void scatter128(const int* __restrict__ ei, const float* __restrict__ dinv,
                           const float* __restrict__ H, float* __restrict__ agg) {
    int idx = blockIdx.x * 256 + threadIdx.x;     // total NE*32, exact
    int e = idx >> 5, q = idx & 31;
    int s = ei[e], d = ei[NE + e];
    float norm = dinv[s] * dinv[d];
    float4 v = *reinterpret_cast<const float4*>(&H[s * 128 + q * 4]);
    float* o = &agg[d * 128 + q * 4];
    unsafeAtomicAdd(o + 0, v.x * norm);
    unsafeAtomicAdd(o + 1, v.y * norm);
    unsafeAtomicAdd(o + 2, v.z * norm);
    unsafeAtomicAdd(o + 3, v.w * norm);
}

// ---------------- edge scatter (40 ch): one float4 per thread ----------------

__global__ void scatter40(const int* __restrict__ ei, const float* __restrict__ dinv,
                          const float* __restrict__ H, float* __restrict__ out) {
    int idx = blockIdx.x * 256 + threadIdx.x;     // total NE*10, exact
    int e = idx / 10, q = idx - e * 10;
    int s = ei[e], d = ei[NE + e];
    float norm = dinv[s] * dinv[d];
    float4 v = *reinterpret_cast<const float4*>(&H[s * 40 + q * 4]);
    float* o = &out[d * 40 + q * 4];
    unsafeAtomicAdd(o + 0, v.x * norm);
    unsafeAtomicAdd(o + 1, v.y * norm);
    unsafeAtomicAdd(o + 2, v.z * norm);
    unsafeAtomicAdd(o + 3, v.w * norm);
}

// ---------------- epilogues: add self-loop + bias (+ReLU layer 1) ----------------

__global__ void epi1(float* __restrict__ h, const float* __restrict__ H1,
                     const float* __restrict__ dinv, const float* __restrict__ b1) {
    int idx = blockIdx.x * 256 + threadIdx.x;     // total NN*32, exact
    int n = idx >> 5, q = idx & 31;
    float di = dinv[n];
    float sl = di * di;
    float4 a  = *reinterpret_cast<const float4*>(&h[n * 128 + q * 4]);
    float4 s  = *reinterpret_cast<const float4*>(&H1[n * 128 + q * 4]);
    float4 bb = *reinterpret_cast<const float4*>(&b1[q * 4]);
    float4 r;
    r.x = fmaxf(fmaf(s.x, sl, a.x + bb.x), 0.f);
    r.y = fmaxf(fmaf(s.y, sl, a.y + bb.y), 0.f);
    r.z = fmaxf(fmaf(s.z, sl, a.z + bb.z), 0.f);
    r.w = fmaxf(fmaf(s.w, sl, a.w + bb.w), 0.f);
    *reinterpret_cast<float4*>(&h[n * 128 + q * 4]) = r;
}

__global__ void epi2(float* __restrict__ out, const float* __restrict__ H2,
                     const float* __restrict__ dinv, const float* __restrict__ b2) {
    int idx = blockIdx.x * 256 + threadIdx.x;     // total NN*10
    if (idx >= NN * 10) return;
    int n = idx / 10, q = idx - n * 10;
    float di = dinv[n];
    float sl = di * di;
    float4 a  = *reinterpret_cast<const float4*>(&out[n * 40 + q * 4]);
    float4 s  = *reinterpret_cast<const float4*>(&H2[n * 40 + q * 4]);
    float4 bb = *reinterpret_cast<const float4*>(&b2[q * 4]);
    float4 r;
    r.x = fmaf(s.x, sl, a.x + bb.x);
    r.y = fmaf(s.y, sl, a.y + bb.y);
    r.z = fmaf(s.z, sl, a.z + bb.z);
    r.w = fmaf(s.w, sl, a.w + bb.w);
    *reinterpret_cast<float4*>(&out[n * 40 + q * 4]) = r;
}

// ---------------- launch ----------------

extern "C" void kernel_launch(void* const* d_in, const int* in_sizes, int n_in,
                              void* d_out, int out_size, void* d_ws, size_t ws_size,
                              hipStream_t stream) {
    const float* x  = (const float*)d_in[0];
    const int*   ei = (const int*)d_in[1];     // [2, NE]: row0 = src, row1 = dst
    const float* W1 = (const float*)d_in[2];
    const float* b1 = (const float*)d_in[3];
    const float* W2 = (const float*)d_in[4];
    const float* b2 = (const float*)d_in[5];
    float* out = (float*)d_out;

    float* ws   = (float*)d_ws;
    float* deg  = ws;                         // NN floats -> becomes dinv in place
    float* H1   = ws + 50048;                 // NN*128
    float* agg1 = H1 + 6400000;               // NN*128 -> becomes h in place
    float* H2   = agg1 + 6400000;             // NN*40

    // degree + dinv
    hipMemsetAsync(deg, 0, NN * sizeof(float), stream);
    deg_kernel<<<(NE + 255) / 256, 256, 0, stream>>>(ei + NE, deg);
    dinv_kernel<<<(NN + 255) / 256, 256, 0, stream>>>(deg);

    // layer 1: H1 = x @ W1
    gemm_k128<<<dim3((NN + 63) / 64, 2), 256, 0, stream>>>(x, W1, H1, NN, 128);
    hipMemsetAsync(agg1, 0, (size_t)NN * 128 * sizeof(float), stream);
    scatter128<<<NE * 32 / 256, 256, 0, stream>>>(ei, deg, H1, agg1);
    epi1<<<NN * 32 / 256, 256, 0, stream>>>(agg1, H1, deg, b1);

    // layer 2: H2 = h @ W2
    gemm_k128<<<dim3((NN + 63) / 64, 1), 256, 0, stream>>>(agg1, W2, H2, NN, 40);
    hipMemsetAsync(out, 0, (size_t)NN * 40 * sizeof(float), stream);
    scatter40<<<NE * 10 / 256, 256, 0, stream>>>(ei, deg, H2, out);
    epi2<<<(NN * 10 + 255) / 256, 256, 0, stream>>>(out, H2, deg, b2);
}

// Round 2
// 405.879 us; speedup vs baseline: 4.1356x; 4.1356x over previous
//
#include <hip/hip_runtime.h>
#include <cstdint>

#define NN 50000
#define NE 640000

// ---------------- CSR build ----------------

__global__ void hist_kernel(const int* __restrict__ dst, int* __restrict__ cnt) {
    int i = blockIdx.x * 256 + threadIdx.x;
    if (i < NE) atomicAdd(&cnt[dst[i]], 1);
}

__global__ void dinv_kernel(const int* __restrict__ cnt, float* __restrict__ dinv) {
    int i = blockIdx.x * 256 + threadIdx.x;
    if (i < NN) dinv[i] = rsqrtf((float)cnt[i] + 1.0f);   // +1 for self-loop
}

// exclusive scan, 256-element blocks (Hillis-Steele in LDS)
__global__ void scan_block(const int* __restrict__ in, int* __restrict__ out,
                           int* __restrict__ partials, int n) {
    __shared__ int sm[256];
    int t = threadIdx.x;
    int gid = blockIdx.x * 256 + t;
    int v = (gid < n) ? in[gid] : 0;
    sm[t] = v;
    __syncthreads();
#pragma unroll
    for (int off = 1; off < 256; off <<= 1) {
        int add = (t >= off) ? sm[t - off] : 0;
        __syncthreads();
        sm[t] += add;
        __syncthreads();
    }
    if (gid < n) out[gid] = sm[t] - v;            // exclusive
    if (t == 255) partials[blockIdx.x] = sm[255];
}

__global__ void scan_partials(int* __restrict__ p, int nb) {
    __shared__ int sm[256];
    int t = threadIdx.x;
    int v = (t < nb) ? p[t] : 0;
    sm[t] = v;
    __syncthreads();
#pragma unroll
    for (int off = 1; off < 256; off <<= 1) {
        int add = (t >= off) ? sm[t - off] : 0;
        __syncthreads();
        sm[t] += add;
        __syncthreads();
    }
    if (t < nb) p[t] = sm[t] - v;                 // exclusive
}

__global__ void finalize_offsets(int* __restrict__ offs, const int* __restrict__ partials,
                                 int* __restrict__ cursor, int n) {
    int gid = blockIdx.x * 256 + threadIdx.x;
    if (gid < n) {
        int v = offs[gid] + partials[blockIdx.x];
        offs[gid] = v;
        cursor[gid] = v;
    }
}

__global__ void csr_fill(const int* __restrict__ ei, const float* __restrict__ dinv,
                         int* __restrict__ cursor, int* __restrict__ csr_src,
                         float* __restrict__ csr_norm) {
    int e = blockIdx.x * 256 + threadIdx.x;
    if (e < NE) {
        int s = ei[e], d = ei[NE + e];
        int pos = atomicAdd(&cursor[d], 1);
        csr_src[pos] = s;
        csr_norm[pos] = dinv[s] * dinv[d];
    }
}

// ---------------- fp32 GEMM, K=128 fixed, 64x64 tile ----------------

__global__ __launch_bounds__(256) void gemm_k128(const float* __restrict__ A,
                                                 const float* __restrict__ B,
                                                 float* __restrict__ C,
                                                 int M, int N) {
    __shared__ float As[64][132];
    __shared__ __align__(16) float Bs[128][64];
    const int t  = threadIdx.x;
    const int m0 = blockIdx.x * 64;
    const int n0 = blockIdx.y * 64;

#pragma unroll
    for (int i = 0; i < 8; ++i) {
        int idx = i * 256 + t;
        int r = idx >> 5, c4 = idx & 31;
        int gm = m0 + r;
        float4 v = make_float4(0.f, 0.f, 0.f, 0.f);
        if (gm < M) v = *reinterpret_cast<const float4*>(&A[gm * 128 + c4 * 4]);
        As[r][c4 * 4 + 0] = v.x;
        As[r][c4 * 4 + 1] = v.y;
        As[r][c4 * 4 + 2] = v.z;
        As[r][c4 * 4 + 3] = v.w;
    }
#pragma unroll
    for (int i = 0; i < 8; ++i) {
        int idx = i * 256 + t;
        int k = idx >> 4, c4 = idx & 15;
        int gn = n0 + c4 * 4;
        float4 v;
        v.x = (gn + 0 < N) ? B[k * N + gn + 0] : 0.f;
        v.y = (gn + 1 < N) ? B[k * N + gn + 1] : 0.f;
        v.z = (gn + 2 < N) ? B[k * N + gn + 2] : 0.f;
        v.w = (gn + 3 < N) ? B[k * N + gn + 3] : 0.f;
        *reinterpret_cast<float4*>(&Bs[k][c4 * 4]) = v;
    }
    __syncthreads();

    const int tx = t & 15, ty = t >> 4;
    float acc[4][4] = {};
#pragma unroll 8
    for (int k = 0; k < 128; ++k) {
        float a0 = As[ty * 4 + 0][k];
        float a1 = As[ty * 4 + 1][k];
        float a2 = As[ty * 4 + 2][k];
        float a3 = As[ty * 4 + 3][k];
        float4 b = *reinterpret_cast<const float4*>(&Bs[k][tx * 4]);
        acc[0][0] += a0 * b.x; acc[0][1] += a0 * b.y; acc[0][2] += a0 * b.z; acc[0][3] += a0 * b.w;
        acc[1][0] += a1 * b.x; acc[1][1] += a1 * b.y; acc[1][2] += a1 * b.z; acc[1][3] += a1 * b.w;
        acc[2][0] += a2 * b.x; acc[2][1] += a2 * b.y; acc[2][2] += a2 * b.z; acc[2][3] += a2 * b.w;
        acc[3][0] += a3 * b.x; acc[3][1] += a3 * b.y; acc[3][2] += a3 * b.z; acc[3][3] += a3 * b.w;
    }

#pragma unroll
    for (int i = 0; i < 4; ++i) {
        int gm = m0 + ty * 4 + i;
        if (gm >= M) continue;
        int gn = n0 + tx * 4;
        if (gn + 3 < N) {
            *reinterpret_cast<float4*>(&C[gm * N + gn]) =
                make_float4(acc[i][0], acc[i][1], acc[i][2], acc[i][3]);
        } else {
#pragma unroll
            for (int j = 0; j < 4; ++j)
                if (gn + j < N) C[gm * N + gn + j] = acc[i][j];
        }
    }
}

// ---------------- gather layer 1 (128 ch) + fused self-loop/bias/ReLU ----------------
// one dst node per 128 threads (2 per block)

__global__ __launch_bounds__(256) void gather128(const int* __restrict__ offs,
                                                 const int* __restrict__ ends,
                                                 const int* __restrict__ csr_src,
                                                 const float* __restrict__ csr_norm,
                                                 const float* __restrict__ H1,
                                                 const float* __restrict__ dinv,
                                                 const float* __restrict__ b1,
                                                 float* __restrict__ h) {
    int ch = threadIdx.x & 127;
    int n = blockIdx.x * 2 + (threadIdx.x >> 7);
    if (n >= NN) return;
    int beg = offs[n], end = ends[n];
    float acc = 0.f;
    for (int j = beg; j < end; ++j) {
        int s   = csr_src[j];           // uniform across the wave -> broadcast
        float w = csr_norm[j];
        acc += H1[s * 128 + ch] * w;    // coalesced 512B per edge
    }
    float di = dinv[n];
    float r = acc + H1[n * 128 + ch] * di * di + b1[ch];
    h[n * 128 + ch] = fmaxf(r, 0.f);
}

// ---------------- gather layer 2 (40 ch) + fused self-loop/bias ----------------
// one dst node per 64 threads (4 per block), lanes 40..63 idle

__global__ __launch_bounds__(256) void gather40(const int* __restrict__ offs,
                                                const int* __restrict__ ends,
                                                const int* __restrict__ csr_src,
                                                const float* __restrict__ csr_norm,
                                                const float* __restrict__ H2,
                                                const float* __restrict__ dinv,
                                                const float* __restrict__ b2,
                                                float* __restrict__ out) {
    int ch = threadIdx.x & 63;
    int n = blockIdx.x * 4 + (threadIdx.x >> 6);
    if (n >= NN || ch >= 40) return;
    int beg = offs[n], end = ends[n];
    float acc = 0.f;
    for (int j = beg; j < end; ++j) {
        int s   = csr_src[j];
        float w = csr_norm[j];
        acc += H2[s * 40 + ch] * w;
    }
    float di = dinv[n];
    out[n * 40 + ch] = acc + H2[n * 40 + ch] * di * di + b2[ch];
}

// ---------------- launch ----------------

extern "C" void kernel_launch(void* const* d_in, const int* in_sizes, int n_in,
                              void* d_out, int out_size, void* d_ws, size_t ws_size,
                              hipStream_t stream) {
    const float* x  = (const float*)d_in[0];
    const int*   ei = (const int*)d_in[1];     // [2, NE]: row0 = src, row1 = dst
    const float* W1 = (const float*)d_in[2];
    const float* b1 = (const float*)d_in[3];
    const float* W2 = (const float*)d_in[4];
    const float* b2 = (const float*)d_in[5];
    float* out = (float*)d_out;

    // workspace layout (4B elements)
    int*   deg_i    = (int*)d_ws;                  // [50048]
    float* dinv     = (float*)d_ws + 50048;        // [50048]
    int*   offs     = (int*)d_ws + 100096;         // [50048]
    int*   cursor   = (int*)d_ws + 150144;         // [50048] -> ends after csr_fill
    int*   partials = (int*)d_ws + 200192;         // [512]
    int*   csr_src  = (int*)d_ws + 200704;         // [640000]
    float* csr_norm = (float*)d_ws + 840704;       // [640000]
    float* H1       = (float*)d_ws + 1480704;      // [6400000] (reused as H2 later)
    float* h        = (float*)d_ws + 7880704;      // [6400000]
    float* H2       = H1;                          // alias: H1 dead after gather128

    const int NB = (NN + 255) / 256;               // 196 scan blocks

    // CSR build
    hipMemsetAsync(deg_i, 0, NN * sizeof(int), stream);
    hist_kernel<<<(NE + 255) / 256, 256, 0, stream>>>(ei + NE, deg_i);
    dinv_kernel<<<NB, 256, 0, stream>>>(deg_i, dinv);
    scan_block<<<NB, 256, 0, stream>>>(deg_i, offs, partials, NN);
    scan_partials<<<1, 256, 0, stream>>>(partials, NB);
    finalize_offsets<<<NB, 256, 0, stream>>>(offs, partials, cursor, NN);
    csr_fill<<<(NE + 255) / 256, 256, 0, stream>>>(ei, dinv, cursor, csr_src, csr_norm);

    // layer 1
    gemm_k128<<<dim3((NN + 63) / 64, 2), 256, 0, stream>>>(x, W1, H1, NN, 128);
    gather128<<<(NN + 1) / 2, 256, 0, stream>>>(offs, cursor, csr_src, csr_norm,
                                                H1, dinv, b1, h);

    // layer 2
    gemm_k128<<<dim3((NN + 63) / 64, 1), 256, 0, stream>>>(h, W2, H2, NN, 40);
    gather40<<<(NN + 3) / 4, 256, 0, stream>>>(offs, cursor, csr_src, csr_norm,
                                               H2, dinv, b2, out);
}

// Round 3
// 299.962 us; speedup vs baseline: 5.5959x; 1.3531x over previous
//
#include <hip/hip_runtime.h>
#include <cstdint>

#define NN 50000
#define NE 640000

// ---------------- CSR build ----------------

__global__ void hist_kernel(const int* __restrict__ dst, int* __restrict__ cnt) {
    int i = blockIdx.x * 256 + threadIdx.x;
    if (i < NE) atomicAdd(&cnt[dst[i]], 1);
}

// exclusive scan, 256-element blocks (Hillis-Steele in LDS)
__global__ void scan_block(const int* __restrict__ in, int* __restrict__ out,
                           int* __restrict__ partials, int n) {
    __shared__ int sm[256];
    int t = threadIdx.x;
    int gid = blockIdx.x * 256 + t;
    int v = (gid < n) ? in[gid] : 0;
    sm[t] = v;
    __syncthreads();
#pragma unroll
    for (int off = 1; off < 256; off <<= 1) {
        int add = (t >= off) ? sm[t - off] : 0;
        __syncthreads();
        sm[t] += add;
        __syncthreads();
    }
    if (gid < n) out[gid] = sm[t] - v;            // exclusive
    if (t == 255) partials[blockIdx.x] = sm[255];
}

__global__ void scan_partials(int* __restrict__ p, int nb) {
    __shared__ int sm[256];
    int t = threadIdx.x;
    int v = (t < nb) ? p[t] : 0;
    sm[t] = v;
    __syncthreads();
#pragma unroll
    for (int off = 1; off < 256; off <<= 1) {
        int add = (t >= off) ? sm[t - off] : 0;
        __syncthreads();
        sm[t] += add;
        __syncthreads();
    }
    if (t < nb) p[t] = sm[t] - v;                 // exclusive
}

// finalize offsets + init cursors + compute dinv (fused)
__global__ void finalize_offsets(int* __restrict__ offs, const int* __restrict__ partials,
                                 int* __restrict__ cursor, const int* __restrict__ cnt,
                                 float* __restrict__ dinv, int n) {
    int gid = blockIdx.x * 256 + threadIdx.x;
    if (gid < n) {
        int v = offs[gid] + partials[blockIdx.x];
        offs[gid] = v;
        cursor[gid] = v;
        dinv[gid] = rsqrtf((float)cnt[gid] + 1.0f);   // +1 for self-loop
    }
}

__global__ void csr_fill(const int* __restrict__ ei, const float* __restrict__ dinv,
                         int* __restrict__ cursor, int* __restrict__ csr_src,
                         float* __restrict__ csr_norm) {
    int e = blockIdx.x * 256 + threadIdx.x;
    if (e < NE) {
        int s = ei[e], d = ei[NE + e];
        int pos = atomicAdd(&cursor[d], 1);
        csr_src[pos] = s;
        csr_norm[pos] = dinv[s] * dinv[d];
    }
}

// ---------------- fp32 GEMM, K=128 fixed, 64x64 tile ----------------

__global__ __launch_bounds__(256) void gemm_k128(const float* __restrict__ A,
                                                 const float* __restrict__ B,
                                                 float* __restrict__ C,
                                                 int M, int N) {
    __shared__ float As[64][132];
    __shared__ __align__(16) float Bs[128][64];
    const int t  = threadIdx.x;
    const int m0 = blockIdx.x * 64;
    const int n0 = blockIdx.y * 64;

#pragma unroll
    for (int i = 0; i < 8; ++i) {
        int idx = i * 256 + t;
        int r = idx >> 5, c4 = idx & 31;
        int gm = m0 + r;
        float4 v = make_float4(0.f, 0.f, 0.f, 0.f);
        if (gm < M) v = *reinterpret_cast<const float4*>(&A[gm * 128 + c4 * 4]);
        As[r][c4 * 4 + 0] = v.x;
        As[r][c4 * 4 + 1] = v.y;
        As[r][c4 * 4 + 2] = v.z;
        As[r][c4 * 4 + 3] = v.w;
    }
#pragma unroll
    for (int i = 0; i < 8; ++i) {
        int idx = i * 256 + t;
        int k = idx >> 4, c4 = idx & 15;
        int gn = n0 + c4 * 4;
        float4 v;
        v.x = (gn + 0 < N) ? B[k * N + gn + 0] : 0.f;
        v.y = (gn + 1 < N) ? B[k * N + gn + 1] : 0.f;
        v.z = (gn + 2 < N) ? B[k * N + gn + 2] : 0.f;
        v.w = (gn + 3 < N) ? B[k * N + gn + 3] : 0.f;
        *reinterpret_cast<float4*>(&Bs[k][c4 * 4]) = v;
    }
    __syncthreads();

    const int tx = t & 15, ty = t >> 4;
    float acc[4][4] = {};
#pragma unroll 8
    for (int k = 0; k < 128; ++k) {
        float a0 = As[ty * 4 + 0][k];
        float a1 = As[ty * 4 + 1][k];
        float a2 = As[ty * 4 + 2][k];
        float a3 = As[ty * 4 + 3][k];
        float4 b = *reinterpret_cast<const float4*>(&Bs[k][tx * 4]);
        acc[0][0] += a0 * b.x; acc[0][1] += a0 * b.y; acc[0][2] += a0 * b.z; acc[0][3] += a0 * b.w;
        acc[1][0] += a1 * b.x; acc[1][1] += a1 * b.y; acc[1][2] += a1 * b.z; acc[1][3] += a1 * b.w;
        acc[2][0] += a2 * b.x; acc[2][1] += a2 * b.y; acc[2][2] += a2 * b.z; acc[2][3] += a2 * b.w;
        acc[3][0] += a3 * b.x; acc[3][1] += a3 * b.y; acc[3][2] += a3 * b.z; acc[3][3] += a3 * b.w;
    }

#pragma unroll
    for (int i = 0; i < 4; ++i) {
        int gm = m0 + ty * 4 + i;
        if (gm >= M) continue;
        int gn = n0 + tx * 4;
        if (gn + 3 < N) {
            *reinterpret_cast<float4*>(&C[gm * N + gn]) =
                make_float4(acc[i][0], acc[i][1], acc[i][2], acc[i][3]);
        } else {
#pragma unroll
            for (int j = 0; j < 4; ++j)
                if (gn + j < N) C[gm * N + gn + j] = acc[i][j];
        }
    }
}

// ---------------- gather layer 1 (128 ch) + fused self-loop/bias/ReLU ----------------
// one dst node per 64-lane wave, lane owns a float2 of channels; edge loop unrolled x4

__global__ __launch_bounds__(256) void gather128(const int* __restrict__ offs,
                                                 const int* __restrict__ ends,
                                                 const int* __restrict__ csr_src,
                                                 const float* __restrict__ csr_norm,
                                                 const float* __restrict__ H1,
                                                 const float* __restrict__ dinv,
                                                 const float* __restrict__ b1,
                                                 float* __restrict__ h) {
    const int lane = threadIdx.x & 63;
    const int n = blockIdx.x * 4 + (threadIdx.x >> 6);
    if (n >= NN) return;
    const int beg = offs[n], end = ends[n];
    float2 acc = make_float2(0.f, 0.f);
    int j = beg;
    const int n4end = beg + ((end - beg) & ~3);
    for (; j < n4end; j += 4) {
        int s0 = csr_src[j + 0], s1 = csr_src[j + 1];
        int s2 = csr_src[j + 2], s3 = csr_src[j + 3];
        float w0 = csr_norm[j + 0], w1 = csr_norm[j + 1];
        float w2 = csr_norm[j + 2], w3 = csr_norm[j + 3];
        float2 v0 = *reinterpret_cast<const float2*>(H1 + (size_t)s0 * 128 + lane * 2);
        float2 v1 = *reinterpret_cast<const float2*>(H1 + (size_t)s1 * 128 + lane * 2);
        float2 v2 = *reinterpret_cast<const float2*>(H1 + (size_t)s2 * 128 + lane * 2);
        float2 v3 = *reinterpret_cast<const float2*>(H1 + (size_t)s3 * 128 + lane * 2);
        acc.x += v0.x * w0 + v1.x * w1 + v2.x * w2 + v3.x * w3;
        acc.y += v0.y * w0 + v1.y * w1 + v2.y * w2 + v3.y * w3;
    }
    for (; j < end; ++j) {
        int s = csr_src[j];
        float w = csr_norm[j];
        float2 v = *reinterpret_cast<const float2*>(H1 + (size_t)s * 128 + lane * 2);
        acc.x += v.x * w;
        acc.y += v.y * w;
    }
    float di = dinv[n];
    float sl = di * di;
    float2 sv = *reinterpret_cast<const float2*>(H1 + (size_t)n * 128 + lane * 2);
    float2 bv = *reinterpret_cast<const float2*>(b1 + lane * 2);
    float2 r;
    r.x = fmaxf(fmaf(sv.x, sl, acc.x + bv.x), 0.f);
    r.y = fmaxf(fmaf(sv.y, sl, acc.y + bv.y), 0.f);
    *reinterpret_cast<float2*>(h + (size_t)n * 128 + lane * 2) = r;
}

// ---------------- gather layer 2 (40 ch) + fused self-loop/bias ----------------
// one dst node per 64 threads (lanes 40..63 idle); edge loop unrolled x4

__global__ __launch_bounds__(256) void gather40(const int* __restrict__ offs,
                                                const int* __restrict__ ends,
                                                const int* __restrict__ csr_src,
                                                const float* __restrict__ csr_norm,
                                                const float* __restrict__ H2,
                                                const float* __restrict__ dinv,
                                                const float* __restrict__ b2,
                                                float* __restrict__ out) {
    const int ch = threadIdx.x & 63;
    const int n = blockIdx.x * 4 + (threadIdx.x >> 6);
    if (n >= NN || ch >= 40) return;
    const int beg = offs[n], end = ends[n];
    float acc = 0.f;
    int j = beg;
    const int n4end = beg + ((end - beg) & ~3);
    for (; j < n4end; j += 4) {
        int s0 = csr_src[j + 0], s1 = csr_src[j + 1];
        int s2 = csr_src[j + 2], s3 = csr_src[j + 3];
        float w0 = csr_norm[j + 0], w1 = csr_norm[j + 1];
        float w2 = csr_norm[j + 2], w3 = csr_norm[j + 3];
        float v0 = H2[(size_t)s0 * 40 + ch];
        float v1 = H2[(size_t)s1 * 40 + ch];
        float v2 = H2[(size_t)s2 * 40 + ch];
        float v3 = H2[(size_t)s3 * 40 + ch];
        acc += v0 * w0 + v1 * w1 + v2 * w2 + v3 * w3;
    }
    for (; j < end; ++j) {
        int s = csr_src[j];
        acc += H2[(size_t)s * 40 + ch] * csr_norm[j];
    }
    float di = dinv[n];
    out[(size_t)n * 40 + ch] = acc + H2[(size_t)n * 40 + ch] * di * di + b2[ch];
}

// ---------------- launch ----------------

extern "C" void kernel_launch(void* const* d_in, const int* in_sizes, int n_in,
                              void* d_out, int out_size, void* d_ws, size_t ws_size,
                              hipStream_t stream) {
    const float* x  = (const float*)d_in[0];
    const int*   ei = (const int*)d_in[1];     // [2, NE]: row0 = src, row1 = dst
    const float* W1 = (const float*)d_in[2];
    const float* b1 = (const float*)d_in[3];
    const float* W2 = (const float*)d_in[4];
    const float* b2 = (const float*)d_in[5];
    float* out = (float*)d_out;

    // workspace layout (4B elements)
    int*   deg_i    = (int*)d_ws;                  // [50048]
    float* dinv     = (float*)d_ws + 50048;        // [50048]
    int*   offs     = (int*)d_ws + 100096;         // [50048]
    int*   cursor   = (int*)d_ws + 150144;         // [50048] -> ends after csr_fill
    int*   partials = (int*)d_ws + 200192;         // [512]
    int*   csr_src  = (int*)d_ws + 200704;         // [640000]
    float* csr_norm = (float*)d_ws + 840704;       // [640000]
    float* H1       = (float*)d_ws + 1480704;      // [6400000] (reused as H2 later)
    float* h        = (float*)d_ws + 7880704;      // [6400000]
    float* H2       = H1;                          // alias: H1 dead after gather128

    const int NB = (NN + 255) / 256;               // 196 scan blocks

    // CSR build
    hipMemsetAsync(deg_i, 0, NN * sizeof(int), stream);
    hist_kernel<<<(NE + 255) / 256, 256, 0, stream>>>(ei + NE, deg_i);
    scan_block<<<NB, 256, 0, stream>>>(deg_i, offs, partials, NN);
    scan_partials<<<1, 256, 0, stream>>>(partials, NB);
    finalize_offsets<<<NB, 256, 0, stream>>>(offs, partials, cursor, deg_i, dinv, NN);
    csr_fill<<<(NE + 255) / 256, 256, 0, stream>>>(ei, dinv, cursor, csr_src, csr_norm);

    // layer 1
    gemm_k128<<<dim3((NN + 63) / 64, 2), 256, 0, stream>>>(x, W1, H1, NN, 128);
    gather128<<<(NN + 3) / 4, 256, 0, stream>>>(offs, cursor, csr_src, csr_norm,
                                                H1, dinv, b1, h);

    // layer 2
    gemm_k128<<<dim3((NN + 63) / 64, 1), 256, 0, stream>>>(h, W2, H2, NN, 40);
    gather40<<<(NN + 3) / 4, 256, 0, stream>>>(offs, cursor, csr_src, csr_norm,
                                               H2, dinv, b2, out);
}